// Round 6
// baseline (2282.342 us; speedup 1.0000x reference)
//
#include <hip/hip_runtime.h>
#include <hip/hip_bf16.h>

#define M_ROWS 65536
#define N_COLS 8192
#define K_DIM  1024
#define CAP    64
#define MARGIN 0.5f   // record threshold vs running min (7.8 sigma of bf16-dot err diff)
#define PRUNE  0.5f   // refine gather threshold vs final recorded min (same bound)
#define NSEG   3      // grid = 512*3 = 1536 = 6 blocks/CU = 2 full rounds of 3-resident

typedef __attribute__((ext_vector_type(8))) short bf16x8;
typedef __attribute__((ext_vector_type(4))) float f32x4;

__device__ __forceinline__ unsigned short f32_to_bf16_rne(float f) {
  unsigned int u = __float_as_uint(f);
  unsigned int r = u + 0x7fffu + ((u >> 16) & 1u);
  return (unsigned short)(r >> 16);
}

// ---- z (fp32) -> bf16, grid-stride; also zeroes counts (ws poisoned 0xAA) ----
__global__ void vq_convert_z(const float* __restrict__ z, unsigned short* __restrict__ zb,
                             int* __restrict__ counts) {
  const int tid    = blockIdx.x * blockDim.x + threadIdx.x;
  const int stride = gridDim.x * blockDim.x;
  if (tid < M_ROWS) counts[tid] = 0;
  const int total = M_ROWS * (K_DIM / 4);
  for (int i = tid; i < total; i += stride) {
    float4 v = ((const float4*)z)[i];
    ushort4 o;
    o.x = f32_to_bf16_rne(v.x);
    o.y = f32_to_bf16_rne(v.y);
    o.z = f32_to_bf16_rne(v.z);
    o.w = f32_to_bf16_rne(v.w);
    ((ushort4*)zb)[i] = o;
  }
}

// ---- transpose codebook [K][N] -> cbT [N][K] fp32 + bf16 ----
__global__ void vq_transpose_cb(const float* __restrict__ cb,
                                float* __restrict__ cbT,
                                unsigned short* __restrict__ cbTb) {
  __shared__ float tile[32][33];
  int n0 = blockIdx.x * 32;
  int k0 = blockIdx.y * 32;
  int tx = threadIdx.x;
  int ty = threadIdx.y;
#pragma unroll
  for (int i = 0; i < 4; ++i) {
    int k = k0 + ty + i * 8;
    tile[ty + i * 8][tx] = cb[(size_t)k * N_COLS + n0 + tx];
  }
  __syncthreads();
#pragma unroll
  for (int i = 0; i < 4; ++i) {
    int n = n0 + ty + i * 8;
    float v = tile[tx][ty + i * 8];
    cbT[(size_t)n * K_DIM + k0 + tx] = v;
    cbTb[(size_t)n * K_DIM + k0 + tx] = f32_to_bf16_rne(v);
  }
}

// ---- fused bf16 MFMA GEMM + per-row running-min + candidate record ----
// grid = (M/128) * NSEG; block = one 128-row stripe x ~21 of 64 col-chunks.
// Per-segment running min: the global-min column is always within MARGIN of
// its own segment's running min, so it is always recorded (with its fp32
// MFMA value, enabling the refine-side prune).
// OCCUPANCY: __launch_bounds__(256,3) -> 80 arch VGPR + 64 acc = 3 blocks/CU
// (verified R3/R4); NSEG=3 grid 1536 = exactly 2 full rounds of 3-resident.
// Staging: global_load_lds width=16, XOR-swizzled global segment so LDS
// fragment reads (ds_read_b128) spread across all 32 banks (2 lanes/bank).
__global__ __launch_bounds__(256, 3) void vq_gemm(const unsigned short* __restrict__ zb,
                                                  const unsigned short* __restrict__ cbTb,
                                                  int* __restrict__ counts,
                                                  unsigned short* __restrict__ cand,
                                                  float* __restrict__ candv) {
  __shared__ __align__(16) unsigned short As[128 * 64];
  __shared__ __align__(16) unsigned short Bs[128 * 64];
  const int tid  = threadIdx.x;
  const int wave = tid >> 6;
  const int lane = tid & 63;
  const int quad = lane >> 4;
  const int l16  = lane & 15;
  // decode: blocks [0,512) = segment 0 over all stripes, then seg 1, seg 2.
  const int b      = blockIdx.x;
  const int seg    = b >> 9;       // [0, NSEG)
  const int stripe = b & 511;      // [0, 512)
  const int row0 = stripe * 128;
  // staging lane roles: row-within-8 = lane>>3, segment = lane&7, swizzled by row&7
  const int rr = lane >> 3;
  const int sgo = (((lane & 7) ^ rr) << 3);  // swizzled k-offset (shorts)
  const int swz = l16 & 7;                   // read-side swizzle key

  float run[2][4];
#pragma unroll
  for (int a = 0; a < 2; ++a)
#pragma unroll
    for (int b2 = 0; b2 < 4; ++b2) run[a][b2] = 1e30f;

  // uneven 3-way split of 64 chunks: 21/21/22
  const int nc0 = (seg * 64) / NSEG;
  const int nc1 = ((seg + 1) * 64) / NSEG;
  for (int nc = nc0; nc < nc1; ++nc) {
    const int col0 = nc * 128;
    f32x4 acc[2][8];
#pragma unroll
    for (int a = 0; a < 2; ++a)
#pragma unroll
      for (int b2 = 0; b2 < 8; ++b2) acc[a][b2] = (f32x4){0.f, 0.f, 0.f, 0.f};

    for (int kk = 0; kk < K_DIM; kk += 64) {
      // wave stages rows [wave*32, wave*32+32) of As and Bs: 4 calls x 8 rows each
      const int rbase = wave * 32;
#pragma unroll
      for (int c = 0; c < 4; ++c) {
        const int r = rbase + c * 8;
        const unsigned short* ga = zb + ((size_t)(row0 + r + rr) << 10) + kk + sgo;
        __builtin_amdgcn_global_load_lds(
            (const __attribute__((address_space(1))) void*)ga,
            (__attribute__((address_space(3))) void*)(As + r * 64), 16, 0, 0);
        const unsigned short* gb = cbTb + ((size_t)(col0 + r + rr) << 10) + kk + sgo;
        __builtin_amdgcn_global_load_lds(
            (const __attribute__((address_space(1))) void*)gb,
            (__attribute__((address_space(3))) void*)(Bs + r * 64), 16, 0, 0);
      }
      __syncthreads();
#pragma unroll
      for (int ks = 0; ks < 2; ++ks) {
        const int koff = (((ks * 4 + quad) ^ swz) << 3);
        const int ma0 = wave * 32 + l16;
        bf16x8 a0 = *(const bf16x8*)(As + ma0 * 64 + koff);
        bf16x8 a1 = *(const bf16x8*)(As + (ma0 + 16) * 64 + koff);
#pragma unroll
        for (int ns = 0; ns < 8; ++ns) {
          bf16x8 bfrag = *(const bf16x8*)(Bs + (ns * 16 + l16) * 64 + koff);
          acc[0][ns] = __builtin_amdgcn_mfma_f32_16x16x32_bf16(a0, bfrag, acc[0][ns], 0, 0, 0);
          acc[1][ns] = __builtin_amdgcn_mfma_f32_16x16x32_bf16(a1, bfrag, acc[1][ns], 0, 0, 0);
        }
      }
      __syncthreads();
    }

    // epilogue: C/D layout row = quad*4 + reg, col = l16 (per 16x16 subtile)
#pragma unroll
    for (int ms = 0; ms < 2; ++ms) {
#pragma unroll
      for (int r = 0; r < 4; ++r) {
        float v = acc[ms][0][r];
#pragma unroll
        for (int ns = 1; ns < 8; ++ns) v = fminf(v, acc[ms][ns][r]);
#pragma unroll
        for (int m = 1; m < 16; m <<= 1) v = fminf(v, __shfl_xor(v, m));
        float rm = fminf(run[ms][r], v);
        run[ms][r] = rm;
        const float thr = rm + MARGIN;
        const int row = row0 + wave * 32 + ms * 16 + quad * 4 + r;
#pragma unroll
        for (int ns = 0; ns < 8; ++ns) {
          if (acc[ms][ns][r] <= thr) {
            int slot = atomicAdd(&counts[row], 1);
            if (slot < CAP) {
              cand [(size_t)row * CAP + slot] = (unsigned short)(col0 + ns * 16 + l16);
              candv[(size_t)row * CAP + slot] = acc[ms][ns][r];
            }
          }
        }
      }
    }
  }
}

// ---- refine: prune by recorded fp32 MFMA value, then exact np-fp32 re-rank ----
// SEMANTICS: reference (ref=np) is z2 @ codebook in fp32 BLAS then argmin
// (first index); sgemm = single fp32 accumulator, k ascending, fused FMA. We
// replicate that bitwise for the pruned candidates (the fmaf ORDER below is
// exactly k-ascending; only LOAD SCHEDULING is pipelined, which cannot change
// the result).
// PERF (R5 lesson): the re-rank loop as a plain load->fmaf loop is LATENCY-
// bound: each of 256 iterations pays ~600cyc of L2-miss latency on the
// scattered candidate-column load -> ~64us/wave -> ~500us fixed dispatch cost
// (the measured ~700us fixed aux). Fix: explicit 8-deep register staging --
// issue 8 independent float4 loads for batch q0+8 while the fmaf chain
// consumes batch q0. Load latency amortizes 8x; chain becomes issue-bound.
__global__ __launch_bounds__(256) void vq_refine(const float* __restrict__ z,
                                                 const float* __restrict__ cbT,
                                                 const int* __restrict__ counts,
                                                 const unsigned short* __restrict__ cand,
                                                 const float* __restrict__ candv,
                                                 float* __restrict__ out) {
  __shared__ float zs[4][K_DIM];
  const int wv   = threadIdx.x >> 6;
  const int row  = blockIdx.x * 4 + wv;
  const int lane = threadIdx.x & 63;
  const float* zr = z + ((size_t)row << 10);
  // stage this wave's z row into LDS (float4, coalesced)
#pragma unroll
  for (int j = 0; j < 4; ++j)
    ((float4*)zs[wv])[j * 64 + lane] = ((const float4*)zr)[j * 64 + lane];
  __syncthreads();

  const int cnt = counts[row];
  float bestv = 1e30f;
  int bestc = 0x7fffffff;
  const float4* z4 = (const float4*)zs[wv];

  if (cnt <= CAP) {
    int   c  = 0x7fffffff;
    float cv = 1e30f;
    if (lane < cnt) {
      c  = (int)cand[(size_t)row * CAP + lane];
      cv = candv[(size_t)row * CAP + lane];
    }
    float vmin = cv;
#pragma unroll
    for (int m = 1; m < 64; m <<= 1) vmin = fminf(vmin, __shfl_xor(vmin, m));
    if (lane < cnt && cv <= vmin + PRUNE) {
      const float4* cb4 = (const float4*)(cbT + ((size_t)c << 10));
      float s = 0.f;
      // software-pipelined, 8 loads in flight; fmaf order strictly k-ascending
      float4 buf[8];
#pragma unroll
      for (int j = 0; j < 8; ++j) buf[j] = cb4[j];
      for (int q0 = 0; q0 < K_DIM / 4; q0 += 8) {
        float4 nxt[8];
        if (q0 + 8 < K_DIM / 4) {
#pragma unroll
          for (int j = 0; j < 8; ++j) nxt[j] = cb4[q0 + 8 + j];
        }
#pragma unroll
        for (int j = 0; j < 8; ++j) {
          float4 zv = z4[q0 + j];
          s = fmaf(zv.x, buf[j].x, s);
          s = fmaf(zv.y, buf[j].y, s);
          s = fmaf(zv.z, buf[j].z, s);
          s = fmaf(zv.w, buf[j].w, s);
        }
#pragma unroll
        for (int j = 0; j < 8; ++j) buf[j] = nxt[j];
      }
      bestv = s;
      bestc = c;
    }
  } else {
    // overflow fallback: full scan, same fp32 semantics (safety net)
    for (int base = 0; base < N_COLS; base += 64) {
      const int c = base + lane;
      const float4* cb4 = (const float4*)(cbT + ((size_t)c << 10));
      float s = 0.f;
      for (int q = 0; q < K_DIM / 4; ++q) {
        float4 cvx = cb4[q];
        float4 zv  = z4[q];
        s = fmaf(zv.x, cvx.x, s);
        s = fmaf(zv.y, cvx.y, s);
        s = fmaf(zv.z, cvx.z, s);
        s = fmaf(zv.w, cvx.w, s);
      }
      if (s < bestv || (s == bestv && c < bestc)) { bestv = s; bestc = c; }
    }
  }

  // lexicographic (value, index) min across 64 lanes => np.argmin semantics
#pragma unroll
  for (int m = 1; m < 64; m <<= 1) {
    float v2 = __shfl_xor(bestv, m);
    int   c2 = __shfl_xor(bestc, m);
    if (v2 < bestv || (v2 == bestv && c2 < bestc)) { bestv = v2; bestc = c2; }
  }
  if (bestc >= N_COLS || bestc < 0) bestc = 0;  // defensive

  const float4* src = (const float4*)(cbT + ((size_t)bestc << 10));
  float4* dst = (float4*)(out + ((size_t)row << 10));
#pragma unroll
  for (int j = 0; j < 4; ++j) dst[j * 64 + lane] = src[j * 64 + lane];
}

// ---- safety net if ws is too small: fp32-seq brute force, no workspace ----
__global__ __launch_bounds__(256) void vq_brute(const float* __restrict__ z,
                                                const float* __restrict__ cb,
                                                float* __restrict__ out) {
  const int row = blockIdx.x;
  __shared__ float zr[K_DIM];
  __shared__ float bv[256];
  __shared__ int bc[256];
  for (int i = threadIdx.x; i < K_DIM; i += 256) zr[i] = z[((size_t)row << 10) + i];
  __syncthreads();
  float bestv = 1e30f;
  int bestc = 0x7fffffff;
  for (int ci = 0; ci < N_COLS / 256; ++ci) {
    int c = ci * 256 + threadIdx.x;
    float s = 0.f;
    for (int k = 0; k < K_DIM; ++k)
      s = fmaf(zr[k], cb[((size_t)k << 13) + c], s);
    if (s < bestv || (s == bestv && c < bestc)) { bestv = s; bestc = c; }
  }
  bv[threadIdx.x] = bestv; bc[threadIdx.x] = bestc;
  __syncthreads();
  for (int sft = 128; sft > 0; sft >>= 1) {
    if (threadIdx.x < sft) {
      float v2 = bv[threadIdx.x + sft]; int c2 = bc[threadIdx.x + sft];
      if (v2 < bv[threadIdx.x] || (v2 == bv[threadIdx.x] && c2 < bc[threadIdx.x])) {
        bv[threadIdx.x] = v2; bc[threadIdx.x] = c2;
      }
    }
    __syncthreads();
  }
  const int c = bc[0];
  for (int d = threadIdx.x; d < K_DIM; d += 256)
    out[((size_t)row << 10) + d] = cb[((size_t)d << 13) + c];
}

extern "C" void kernel_launch(void* const* d_in, const int* in_sizes, int n_in,
                              void* d_out, int out_size, void* d_ws, size_t ws_size,
                              hipStream_t stream) {
  const float* z  = (const float*)d_in[0];
  const float* cb = (const float*)d_in[1];
  float* out = (float*)d_out;

  const size_t zb_bytes     = (size_t)M_ROWS * K_DIM * 2;  // 128 MB
  const size_t cbT_bytes    = (size_t)N_COLS * K_DIM * 4;  // 32 MB
  const size_t cbTb_bytes   = (size_t)N_COLS * K_DIM * 2;  // 16 MB
  const size_t cand_bytes   = (size_t)M_ROWS * CAP * 2;    // 8 MB (u16 indices)
  const size_t candv_bytes  = (size_t)M_ROWS * CAP * 4;    // 16 MB (f32 values)
  const size_t counts_bytes = (size_t)M_ROWS * 4;          // 256 KB
  const size_t need = zb_bytes + cbT_bytes + cbTb_bytes + cand_bytes + candv_bytes + counts_bytes;

  if (ws_size < need) {
    vq_brute<<<M_ROWS, 256, 0, stream>>>(z, cb, out);
    return;
  }

  char* p = (char*)d_ws;
  unsigned short* zb    = (unsigned short*)p; p += zb_bytes;
  float*          cbT   = (float*)p;          p += cbT_bytes;
  unsigned short* cbTb  = (unsigned short*)p; p += cbTb_bytes;
  unsigned short* cand  = (unsigned short*)p; p += cand_bytes;
  float*          candv = (float*)p;          p += candv_bytes;
  int*            counts = (int*)p;

  vq_convert_z<<<2048, 256, 0, stream>>>(z, zb, counts);
  vq_transpose_cb<<<dim3(N_COLS / 32, K_DIM / 32), dim3(32, 8), 0, stream>>>(cb, cbT, cbTb);
  vq_gemm<<<(M_ROWS / 128) * NSEG, 256, 0, stream>>>(zb, cbTb, counts, cand, candv);
  vq_refine<<<M_ROWS / 4, 256, 0, stream>>>(z, cbT, counts, cand, candv, out);
}

// Round 7
// 2031.385 us; speedup vs baseline: 1.1235x; 1.1235x over previous
//
#include <hip/hip_runtime.h>
#include <hip/hip_bf16.h>

#define M_ROWS 65536
#define N_COLS 8192
#define K_DIM  1024
#define CAP    64
#define MARGIN 0.5f   // record threshold vs running min (~29 sigma of pairwise err diff)
#define GAPTHR 0.3f   // decide/prune threshold (~17 sigma of pairwise err diff)
#define NSEG   3      // grid = 512*3 = 1536 = 6 blocks/CU = 2 full rounds of 3-resident

typedef __attribute__((ext_vector_type(8))) short bf16x8;
typedef __attribute__((ext_vector_type(4))) float f32x4;

__device__ __forceinline__ unsigned short f32_to_bf16_rne(float f) {
  unsigned int u = __float_as_uint(f);
  unsigned int r = u + 0x7fffu + ((u >> 16) & 1u);
  return (unsigned short)(r >> 16);
}

// ---- z (fp32) -> bf16, grid-stride; also zeroes counts (ws poisoned 0xAA) ----
__global__ void vq_convert_z(const float* __restrict__ z, unsigned short* __restrict__ zb,
                             int* __restrict__ counts) {
  const int tid    = blockIdx.x * blockDim.x + threadIdx.x;
  const int stride = gridDim.x * blockDim.x;
  if (tid < M_ROWS) counts[tid] = 0;
  const int total = M_ROWS * (K_DIM / 4);
  for (int i = tid; i < total; i += stride) {
    float4 v = ((const float4*)z)[i];
    ushort4 o;
    o.x = f32_to_bf16_rne(v.x);
    o.y = f32_to_bf16_rne(v.y);
    o.z = f32_to_bf16_rne(v.z);
    o.w = f32_to_bf16_rne(v.w);
    ((ushort4*)zb)[i] = o;
  }
}

// ---- transpose codebook [K][N] -> cbT [N][K] fp32 + bf16 ----
__global__ void vq_transpose_cb(const float* __restrict__ cb,
                                float* __restrict__ cbT,
                                unsigned short* __restrict__ cbTb) {
  __shared__ float tile[32][33];
  int n0 = blockIdx.x * 32;
  int k0 = blockIdx.y * 32;
  int tx = threadIdx.x;
  int ty = threadIdx.y;
#pragma unroll
  for (int i = 0; i < 4; ++i) {
    int k = k0 + ty + i * 8;
    tile[ty + i * 8][tx] = cb[(size_t)k * N_COLS + n0 + tx];
  }
  __syncthreads();
#pragma unroll
  for (int i = 0; i < 4; ++i) {
    int n = n0 + ty + i * 8;
    float v = tile[tx][ty + i * 8];
    cbT[(size_t)n * K_DIM + k0 + tx] = v;
    cbTb[(size_t)n * K_DIM + k0 + tx] = f32_to_bf16_rne(v);
  }
}

// ---- fused bf16 MFMA GEMM + per-row running-min + candidate record ----
// UNCHANGED from R4/R5/R6 (verified at its structure's ceiling: MfmaUtil ~37%,
// 3 blocks/CU, grid 1536 = 2 full occupancy rounds).
__global__ __launch_bounds__(256, 3) void vq_gemm(const unsigned short* __restrict__ zb,
                                                  const unsigned short* __restrict__ cbTb,
                                                  int* __restrict__ counts,
                                                  unsigned short* __restrict__ cand,
                                                  float* __restrict__ candv) {
  __shared__ __align__(16) unsigned short As[128 * 64];
  __shared__ __align__(16) unsigned short Bs[128 * 64];
  const int tid  = threadIdx.x;
  const int wave = tid >> 6;
  const int lane = tid & 63;
  const int quad = lane >> 4;
  const int l16  = lane & 15;
  const int b      = blockIdx.x;
  const int seg    = b >> 9;       // [0, NSEG)
  const int stripe = b & 511;      // [0, 512)
  const int row0 = stripe * 128;
  const int rr = lane >> 3;
  const int sgo = (((lane & 7) ^ rr) << 3);  // swizzled k-offset (shorts)
  const int swz = l16 & 7;                   // read-side swizzle key

  float run[2][4];
#pragma unroll
  for (int a = 0; a < 2; ++a)
#pragma unroll
    for (int b2 = 0; b2 < 4; ++b2) run[a][b2] = 1e30f;

  const int nc0 = (seg * 64) / NSEG;
  const int nc1 = ((seg + 1) * 64) / NSEG;
  for (int nc = nc0; nc < nc1; ++nc) {
    const int col0 = nc * 128;
    f32x4 acc[2][8];
#pragma unroll
    for (int a = 0; a < 2; ++a)
#pragma unroll
      for (int b2 = 0; b2 < 8; ++b2) acc[a][b2] = (f32x4){0.f, 0.f, 0.f, 0.f};

    for (int kk = 0; kk < K_DIM; kk += 64) {
      const int rbase = wave * 32;
#pragma unroll
      for (int c = 0; c < 4; ++c) {
        const int r = rbase + c * 8;
        const unsigned short* ga = zb + ((size_t)(row0 + r + rr) << 10) + kk + sgo;
        __builtin_amdgcn_global_load_lds(
            (const __attribute__((address_space(1))) void*)ga,
            (__attribute__((address_space(3))) void*)(As + r * 64), 16, 0, 0);
        const unsigned short* gb = cbTb + ((size_t)(col0 + r + rr) << 10) + kk + sgo;
        __builtin_amdgcn_global_load_lds(
            (const __attribute__((address_space(1))) void*)gb,
            (__attribute__((address_space(3))) void*)(Bs + r * 64), 16, 0, 0);
      }
      __syncthreads();
#pragma unroll
      for (int ks = 0; ks < 2; ++ks) {
        const int koff = (((ks * 4 + quad) ^ swz) << 3);
        const int ma0 = wave * 32 + l16;
        bf16x8 a0 = *(const bf16x8*)(As + ma0 * 64 + koff);
        bf16x8 a1 = *(const bf16x8*)(As + (ma0 + 16) * 64 + koff);
#pragma unroll
        for (int ns = 0; ns < 8; ++ns) {
          bf16x8 bfrag = *(const bf16x8*)(Bs + (ns * 16 + l16) * 64 + koff);
          acc[0][ns] = __builtin_amdgcn_mfma_f32_16x16x32_bf16(a0, bfrag, acc[0][ns], 0, 0, 0);
          acc[1][ns] = __builtin_amdgcn_mfma_f32_16x16x32_bf16(a1, bfrag, acc[1][ns], 0, 0, 0);
        }
      }
      __syncthreads();
    }

#pragma unroll
    for (int ms = 0; ms < 2; ++ms) {
#pragma unroll
      for (int r = 0; r < 4; ++r) {
        float v = acc[ms][0][r];
#pragma unroll
        for (int ns = 1; ns < 8; ++ns) v = fminf(v, acc[ms][ns][r]);
#pragma unroll
        for (int m = 1; m < 16; m <<= 1) v = fminf(v, __shfl_xor(v, m));
        float rm = fminf(run[ms][r], v);
        run[ms][r] = rm;
        const float thr = rm + MARGIN;
        const int row = row0 + wave * 32 + ms * 16 + quad * 4 + r;
#pragma unroll
        for (int ns = 0; ns < 8; ++ns) {
          if (acc[ms][ns][r] <= thr) {
            int slot = atomicAdd(&counts[row], 1);
            if (slot < CAP) {
              cand [(size_t)row * CAP + slot] = (unsigned short)(col0 + ns * 16 + l16);
              candv[(size_t)row * CAP + slot] = acc[ms][ns][r];
            }
          }
        }
      }
    }
  }
}

// ---- decide: pick np-fp32 argmin per row; chain only on ambiguous rows ----
// Recorded values are fp32-MFMA dots; vs the np-fp32 reference dot the
// pairwise error DIFFERENCE has sigma ~0.017 (bf16 quant of z & cb columns
// dominate; accumulation-rounding diff ~1e-5). If the recorded min is unique
// and the runner-up gap > GAPTHR=0.3 (17 sigma), the recorded argmin IS the
// np argmin -- no re-rank (~88% of rows by order-stat spacing). Otherwise:
// bit-exact np-fp32 chain (k-ascending fmaf, single accumulator = BLAS sgemm
// element semantics) on lanes within GAPTHR of the min, dual-stream software-
// pipelined (8 loads in flight), then lexicographic (value,index) reduce =
// np.argmin first-occurrence. One wave per row, grid-stride; no LDS/barrier;
// z touched only on the chain path.
__global__ __launch_bounds__(256) void vq_decide(const float* __restrict__ z,
                                                 const float* __restrict__ cbT,
                                                 const int* __restrict__ counts,
                                                 const unsigned short* __restrict__ cand,
                                                 const float* __restrict__ candv,
                                                 int* __restrict__ bestc_out) {
  const int gtid   = blockIdx.x * blockDim.x + threadIdx.x;
  const int wid    = gtid >> 6;
  const int lane   = gtid & 63;
  const int nwaves = (gridDim.x * blockDim.x) >> 6;

  for (int row = wid; row < M_ROWS; row += nwaves) {
    const int cnt = counts[row];
    const float4* z4g = (const float4*)(z + ((size_t)row << 10));
    int best;

    if (cnt <= CAP) {
      int   c  = 0x7fffffff;
      float cv = 1e30f;
      if (lane < cnt) {
        c  = (int)cand[(size_t)row * CAP + lane];
        cv = candv[(size_t)row * CAP + lane];
      }
      // lexicographic (value, index) min over recorded pairs
      float vmin = cv; int cmin = c;
#pragma unroll
      for (int m = 1; m < 64; m <<= 1) {
        float v2 = __shfl_xor(vmin, m);
        int   c2 = __shfl_xor(cmin, m);
        if (v2 < vmin || (v2 == vmin && c2 < cmin)) { vmin = v2; cmin = c2; }
      }
      // multiplicity of the min and runner-up value
      unsigned long long tie = __ballot(cv == vmin);
      float cv2 = (cv == vmin) ? 1e30f : cv;
      float vsec = cv2;
#pragma unroll
      for (int m = 1; m < 64; m <<= 1) vsec = fminf(vsec, __shfl_xor(vsec, m));

      if (__popcll(tie) == 1 && vsec - vmin > GAPTHR) {
        best = cmin;  // decided without re-rank
      } else {
        // np-fp32 chain on ambiguous lanes (includes the min lane)
        float rv = 1e30f; int rc = 0x7fffffff;
        if (lane < cnt && cv <= vmin + GAPTHR) {
          const float4* cb4 = (const float4*)(cbT + ((size_t)c << 10));
          float s = 0.f;
          float4 cbuf[4], zbuf[4];
#pragma unroll
          for (int j = 0; j < 4; ++j) { cbuf[j] = cb4[j]; zbuf[j] = z4g[j]; }
          for (int q0 = 0; q0 < K_DIM / 4; q0 += 4) {
            float4 cn[4], zn[4];
            if (q0 + 4 < K_DIM / 4) {
#pragma unroll
              for (int j = 0; j < 4; ++j) { cn[j] = cb4[q0 + 4 + j]; zn[j] = z4g[q0 + 4 + j]; }
            }
#pragma unroll
            for (int j = 0; j < 4; ++j) {
              s = fmaf(zbuf[j].x, cbuf[j].x, s);
              s = fmaf(zbuf[j].y, cbuf[j].y, s);
              s = fmaf(zbuf[j].z, cbuf[j].z, s);
              s = fmaf(zbuf[j].w, cbuf[j].w, s);
            }
#pragma unroll
            for (int j = 0; j < 4; ++j) { cbuf[j] = cn[j]; zbuf[j] = zn[j]; }
          }
          rv = s; rc = c;
        }
#pragma unroll
        for (int m = 1; m < 64; m <<= 1) {
          float v2 = __shfl_xor(rv, m);
          int   c2 = __shfl_xor(rc, m);
          if (v2 < rv || (v2 == rv && c2 < rc)) { rv = v2; rc = c2; }
        }
        best = rc;
      }
    } else {
      // overflow fallback: full scan, np-fp32 semantics (safety net)
      float rv = 1e30f; int rc = 0x7fffffff;
      for (int base = 0; base < N_COLS; base += 64) {
        const int cc = base + lane;
        const float4* cb4 = (const float4*)(cbT + ((size_t)cc << 10));
        float s = 0.f;
        for (int q = 0; q < K_DIM / 4; ++q) {
          float4 cv4 = cb4[q];
          float4 zv  = z4g[q];
          s = fmaf(zv.x, cv4.x, s);
          s = fmaf(zv.y, cv4.y, s);
          s = fmaf(zv.z, cv4.z, s);
          s = fmaf(zv.w, cv4.w, s);
        }
        if (s < rv || (s == rv && cc < rc)) { rv = s; rc = cc; }
      }
#pragma unroll
      for (int m = 1; m < 64; m <<= 1) {
        float v2 = __shfl_xor(rv, m);
        int   c2 = __shfl_xor(rc, m);
        if (v2 < rv || (v2 == rv && c2 < rc)) { rv = v2; rc = c2; }
      }
      best = rc;
    }

    if (best >= N_COLS || best < 0) best = 0;  // defensive
    if (lane == 0) bestc_out[row] = best;
  }
}

// ---- gather: out[row] = cbT[bestc[row]] -- pure streaming copy ----
__global__ __launch_bounds__(256) void vq_gather(const float* __restrict__ cbT,
                                                 const int* __restrict__ bestc,
                                                 float* __restrict__ out) {
  const int gtid   = blockIdx.x * blockDim.x + threadIdx.x;
  const int wid    = gtid >> 6;
  const int lane   = gtid & 63;
  const int nwaves = (gridDim.x * blockDim.x) >> 6;
  for (int row = wid; row < M_ROWS; row += nwaves) {
    int c = bestc[row];
    if (c < 0 || c >= N_COLS) c = 0;  // defensive
    const float4* src = (const float4*)(cbT + ((size_t)c << 10));
    float4* dst = (float4*)(out + ((size_t)row << 10));
#pragma unroll
    for (int j = 0; j < 4; ++j) dst[j * 64 + lane] = src[j * 64 + lane];
  }
}

// ---- safety net if ws is too small: fp32-seq brute force, no workspace ----
__global__ __launch_bounds__(256) void vq_brute(const float* __restrict__ z,
                                                const float* __restrict__ cb,
                                                float* __restrict__ out) {
  const int row = blockIdx.x;
  __shared__ float zr[K_DIM];
  __shared__ float bv[256];
  __shared__ int bc[256];
  for (int i = threadIdx.x; i < K_DIM; i += 256) zr[i] = z[((size_t)row << 10) + i];
  __syncthreads();
  float bestv = 1e30f;
  int bestc = 0x7fffffff;
  for (int ci = 0; ci < N_COLS / 256; ++ci) {
    int c = ci * 256 + threadIdx.x;
    float s = 0.f;
    for (int k = 0; k < K_DIM; ++k)
      s = fmaf(zr[k], cb[((size_t)k << 13) + c], s);
    if (s < bestv || (s == bestv && c < bestc)) { bestv = s; bestc = c; }
  }
  bv[threadIdx.x] = bestv; bc[threadIdx.x] = bestc;
  __syncthreads();
  for (int sft = 128; sft > 0; sft >>= 1) {
    if (threadIdx.x < sft) {
      float v2 = bv[threadIdx.x + sft]; int c2 = bc[threadIdx.x + sft];
      if (v2 < bv[threadIdx.x] || (v2 == bv[threadIdx.x] && c2 < bc[threadIdx.x])) {
        bv[threadIdx.x] = v2; bc[threadIdx.x] = c2;
      }
    }
    __syncthreads();
  }
  const int c = bc[0];
  for (int d = threadIdx.x; d < K_DIM; d += 256)
    out[((size_t)row << 10) + d] = cb[((size_t)d << 13) + c];
}

extern "C" void kernel_launch(void* const* d_in, const int* in_sizes, int n_in,
                              void* d_out, int out_size, void* d_ws, size_t ws_size,
                              hipStream_t stream) {
  const float* z  = (const float*)d_in[0];
  const float* cb = (const float*)d_in[1];
  float* out = (float*)d_out;

  const size_t zb_bytes     = (size_t)M_ROWS * K_DIM * 2;  // 128 MB
  const size_t cbT_bytes    = (size_t)N_COLS * K_DIM * 4;  // 32 MB
  const size_t cbTb_bytes   = (size_t)N_COLS * K_DIM * 2;  // 16 MB
  const size_t cand_bytes   = (size_t)M_ROWS * CAP * 2;    // 8 MB (u16 indices)
  const size_t candv_bytes  = (size_t)M_ROWS * CAP * 4;    // 16 MB (f32 values)
  const size_t counts_bytes = (size_t)M_ROWS * 4;          // 256 KB
  const size_t bestc_bytes  = (size_t)M_ROWS * 4;          // 256 KB
  const size_t need = zb_bytes + cbT_bytes + cbTb_bytes + cand_bytes + candv_bytes +
                      counts_bytes + bestc_bytes;

  if (ws_size < need) {
    vq_brute<<<M_ROWS, 256, 0, stream>>>(z, cb, out);
    return;
  }

  char* p = (char*)d_ws;
  unsigned short* zb    = (unsigned short*)p; p += zb_bytes;
  float*          cbT   = (float*)p;          p += cbT_bytes;
  unsigned short* cbTb  = (unsigned short*)p; p += cbTb_bytes;
  unsigned short* cand  = (unsigned short*)p; p += cand_bytes;
  float*          candv = (float*)p;          p += candv_bytes;
  int*            counts = (int*)p;           p += counts_bytes;
  int*            bestc  = (int*)p;

  vq_convert_z<<<2048, 256, 0, stream>>>(z, zb, counts);
  vq_transpose_cb<<<dim3(N_COLS / 32, K_DIM / 32), dim3(32, 8), 0, stream>>>(cb, cbT, cbTb);
  vq_gemm<<<(M_ROWS / 128) * NSEG, 256, 0, stream>>>(zb, cbTb, counts, cand, candv);
  vq_decide<<<2048, 256, 0, stream>>>(z, cbT, counts, cand, candv, bestc);
  vq_gather<<<2048, 256, 0, stream>>>(cbT, bestc, out);
}